// Round 4
// baseline (53.413 us; speedup 1.0000x reference)
//
#include <hip/hip_runtime.h>
#include <math.h>

// NonLinearReadoutBlock, round 4: coalesced global->reg, bf16 convert,
// XOR-swizzled wave-private LDS staging, ds_read_b128 fragments, MFMA layer-1.
// No __syncthreads anywhere (all LDS is wave-private, ordered by lgkmcnt(0)).
//
// Swizzle: within a row (1024 B of bf16), byte' = byte ^ ((row&7)<<4).
// Involution, touches only bits 4-6 -> every 16B/8B access stays contiguous,
// and all fragment-read patterns become quad-balanced (8 lanes/quad = min).

typedef short  bf16x8 __attribute__((ext_vector_type(8)));
typedef short  short4v __attribute__((ext_vector_type(4)));
typedef float  f32x4  __attribute__((ext_vector_type(4)));

static __device__ __forceinline__ short f2bf(float f) {
    union { float f; unsigned u; } v; v.f = f;
    return (short)((v.u + 0x8000u) >> 16);
}

#define BLOCK 256

__global__ __launch_bounds__(BLOCK, 2) void nlrb_kernel(
    const float* __restrict__ x,
    const float* __restrict__ W1s,   // (128,32)
    const float* __restrict__ W1v,   // (128,16)
    const float* __restrict__ b1s,   // (32)
    const float* __restrict__ W2s,   // (16,10)
    const float* __restrict__ W2v,   // (16)
    const float* __restrict__ b2s,   // (10)
    float* __restrict__ out,         // (N,13)
    int N)
{
    // per-wave 16 KB region: holds the bf16 x-tile [16 rows][512 cols] during
    // layer-1; overlaid by the f32 sred scratch [16][68] during layer-2.
    __shared__ __align__(16) char smem[4][16384];

    const int tid  = threadIdx.x;
    const int wave = tid >> 6;
    const int lane = tid & 63;
    const int mq   = lane >> 4;   // k-chunk group (A-fragment row of 8 k's)
    const int o    = lane & 15;   // A row / B col
    const float inv1 = 0.08838834764831843f;  // 1/sqrt(128)
    char* const wbase = smem[wave];

    // ---- one-time: resident B fragments (bf16) ----
    bf16x8 bS0[4], bS1[4], bV[4];
    #pragma unroll
    for (int kb = 0; kb < 4; ++kb) {
        #pragma unroll
        for (int j = 0; j < 8; ++j) {
            const int k = kb * 32 + mq * 8 + j;
            bS0[kb][j] = f2bf(W1s[k * 32 + o]);
            bS1[kb][j] = f2bf(W1s[k * 32 + 16 + o]);
            bV [kb][j] = f2bf(W1v[k * 16 + o]);
        }
    }
    // ---- one-time: layer-2 weights (fp32, per-lane) ----
    const int e = o;
    float wcr[16];
    #pragma unroll
    for (int j = 0; j < 16; ++j)
        wcr[j] = (e < 10) ? W2s[j * 10 + e] : W2v[j];
    const float b2e = (e < 10) ? b2s[e] : 0.0f;
    const float b1a = b1s[o];
    const float b1b = b1s[16 + o];

    const int NT = N >> 4;                 // 6250 16-row tiles
    const int wstride = gridDim.x << 2;
    const int wt0 = (blockIdx.x << 2) + wave;
    const int sw = (o & 7) << 4;           // read-side swizzle key

    // ---- prologue: coalesced loads of tile wt0 (1 KB dense per instr) ----
    float4 L[32];
    if (wt0 < NT) {
        const float4* src = (const float4*)(x + (size_t)(wt0 << 4) * 512);
        #pragma unroll
        for (int s = 0; s < 32; ++s)
            L[s] = src[s * 64 + lane];
    }

    for (int wt = wt0; wt < NT; wt += wstride) {
        const int base = wt << 4;

        // ---- stage: convert to bf16, swizzled ds_write_b64 ----
        #pragma unroll
        for (int s = 0; s < 32; ++s) {
            const int F = s * 256 + lane * 4;       // tile-relative float idx
            const int r = F >> 9;                   // row 0..15
            const int byte = r * 1024 + (((F & 511) * 2) ^ ((r & 7) << 4));
            short4v h;
            h[0] = f2bf(L[s].x); h[1] = f2bf(L[s].y);
            h[2] = f2bf(L[s].z); h[3] = f2bf(L[s].w);
            *(short4v*)(wbase + byte) = h;
        }

        // ---- issue next tile's coalesced loads (hide under compute) ----
        const int nxt = wt + wstride;
        if (nxt < NT) {
            const float4* src = (const float4*)(x + (size_t)(nxt << 4) * 512);
            #pragma unroll
            for (int s = 0; s < 32; ++s)
                L[s] = src[s * 64 + lane];
        }

        asm volatile("s_waitcnt lgkmcnt(0)" ::: "memory");  // writes visible

        // ---- fragment reads + MFMA ----
        const char* rb = wbase + o * 1024;
        f32x4 accS0 = {0.f,0.f,0.f,0.f}, accS1 = {0.f,0.f,0.f,0.f};
        f32x4 accV0 = {0.f,0.f,0.f,0.f}, accV1 = {0.f,0.f,0.f,0.f};
        f32x4 accV2 = {0.f,0.f,0.f,0.f};

        #pragma unroll
        for (int kb = 0; kb < 4; ++kb) {
            bf16x8 a = *(const bf16x8*)(rb + ((kb * 64 + mq * 16) ^ sw));
            accS0 = __builtin_amdgcn_mfma_f32_16x16x32_bf16(a, bS0[kb], accS0, 0, 0, 0);
            accS1 = __builtin_amdgcn_mfma_f32_16x16x32_bf16(a, bS1[kb], accS1, 0, 0, 0);
        }
        #pragma unroll
        for (int kb = 0; kb < 4; ++kb) {
            short t[24];
            #pragma unroll
            for (int q = 0; q < 3; ++q) {
                bf16x8 tq = *(const bf16x8*)(
                    rb + ((256 + kb * 192 + mq * 48 + q * 16) ^ sw));
                #pragma unroll
                for (int i = 0; i < 8; ++i) t[q * 8 + i] = tq[i];
            }
            bf16x8 a0, a1, a2;
            #pragma unroll
            for (int j = 0; j < 8; ++j) {
                a0[j] = t[3 * j + 0];
                a1[j] = t[3 * j + 1];
                a2[j] = t[3 * j + 2];
            }
            accV0 = __builtin_amdgcn_mfma_f32_16x16x32_bf16(a0, bV[kb], accV0, 0, 0, 0);
            accV1 = __builtin_amdgcn_mfma_f32_16x16x32_bf16(a1, bV[kb], accV1, 0, 0, 0);
            accV2 = __builtin_amdgcn_mfma_f32_16x16x32_bf16(a2, bV[kb], accV2, 0, 0, 0);
        }

        asm volatile("s_waitcnt lgkmcnt(0)" ::: "memory");  // x-tile reads done;
                                                            // safe to overlay sred
        // ---- epilogue: lane-local silu + gating -> sred (overlay region) ----
        float* const sredw = (float*)wbase;    // [16][68] f32, 4352 B
        #pragma unroll
        for (int v = 0; v < 4; ++v) {
            const float hs = fmaf(accS0[v], inv1, b1a);
            const float hg = fmaf(accS1[v], inv1, b1b);
            const float s  = hs / (1.f + __expf(-hs));
            const float g  = hg / (1.f + __expf(-hg));
            const float gm = g * inv1;
            const int  r   = mq * 4 + v;
            sredw[r * 68 + o]      = s;
            sredw[r * 68 + 16 + o] = gm * accV0[v];
            sredw[r * 68 + 32 + o] = gm * accV1[v];
            sredw[r * 68 + 48 + o] = gm * accV2[v];
        }
        asm volatile("s_waitcnt lgkmcnt(0)" ::: "memory");

        // ---- layer 2: lane e<13 does dot-16 for rows mq, mq+4, mq+8, mq+12
        #pragma unroll
        for (int w = 0; w < 4; ++w) {
            const int r = (w << 2) + mq;
            if (e < 13) {
                const int slot = (e < 10) ? 0 : (e - 9);
                const float4* p = (const float4*)(sredw + r * 68 + slot * 16);
                float sum = 0.f;
                #pragma unroll
                for (int q = 0; q < 4; ++q) {
                    float4 pv = p[q];
                    sum = fmaf(pv.x, wcr[q * 4 + 0], sum);
                    sum = fmaf(pv.y, wcr[q * 4 + 1], sum);
                    sum = fmaf(pv.z, wcr[q * 4 + 2], sum);
                    sum = fmaf(pv.w, wcr[q * 4 + 3], sum);
                }
                out[(size_t)(base + r) * 13 + e] = fmaf(sum, 0.25f, b2e);
            }
        }
        asm volatile("s_waitcnt lgkmcnt(0)" ::: "memory");  // sred reads done
                                                            // before next staging
    }
}

extern "C" void kernel_launch(void* const* d_in, const int* in_sizes, int n_in,
                              void* d_out, int out_size, void* d_ws, size_t ws_size,
                              hipStream_t stream) {
    const float* x   = (const float*)d_in[0];
    const float* W1s = (const float*)d_in[1];
    const float* W1v = (const float*)d_in[2];
    const float* b1s = (const float*)d_in[3];
    const float* W2s = (const float*)d_in[4];
    const float* W2v = (const float*)d_in[5];
    const float* b2s = (const float*)d_in[6];
    float* outp = (float*)d_out;
    const int N = in_sizes[0] / 512;   // 100000
    nlrb_kernel<<<dim3(512), dim3(BLOCK), 0, stream>>>(
        x, W1s, W1v, b1s, W2s, W2v, b2s, outp, N);
}

// Round 5
// 47.963 us; speedup vs baseline: 1.1136x; 1.1136x over previous
//
#include <hip/hip_runtime.h>
#include <math.h>

// NonLinearReadoutBlock, round 5: round-3 MFMA structure + 1-deep software
// pipeline. Next tile's raw f32 lives in 128 VGPRs; each k-block converts
// (cvt_pk_bf16 + v_perm stride-3 de-interleave), reissues its loads for the
// following tile, and feeds MFMA immediately (transient fragments).
// Peak VGPR ~240 -> 8 waves/CU. Wave-private LDS only (no barriers in loop).

typedef short  bf16x8 __attribute__((ext_vector_type(8)));
typedef int    i32x4  __attribute__((ext_vector_type(4)));
typedef float  f32x4  __attribute__((ext_vector_type(4)));

static __device__ __forceinline__ short f2bf(float f) {
    union { float f; unsigned u; } v; v.f = f;
    return (short)((v.u + 0x8000u) >> 16);
}
static __device__ __forceinline__ unsigned cvtpk(float lo, float hi) {
    unsigned r;
    asm("v_cvt_pk_bf16_f32 %0, %1, %2" : "=v"(r) : "v"(lo), "v"(hi));
    return r;   // {lo16: bf16(lo), hi16: bf16(hi)}
}

#define BLOCK 256

__global__ __launch_bounds__(BLOCK, 2) void nlrb_kernel(
    const float* __restrict__ x,
    const float* __restrict__ W1s,   // (128,32)
    const float* __restrict__ W1v,   // (128,16)
    const float* __restrict__ b1s,   // (32)
    const float* __restrict__ W2s,   // (16,10)
    const float* __restrict__ W2v,   // (16)
    const float* __restrict__ b2s,   // (10)
    float* __restrict__ out,         // (N,13)
    int N)
{
    __shared__ float sred[4][16][68];   // wave-private layer-2 scratch, 17.4 KB

    const int tid  = threadIdx.x;
    const int wave = tid >> 6;
    const int lane = tid & 63;
    const int mq   = lane >> 4;   // k-chunk group
    const int o    = lane & 15;   // A row / B col
    const float inv1 = 0.08838834764831843f;  // 1/sqrt(128)

    // ---- one-time: resident B fragments (bf16) ----
    bf16x8 bS0[4], bS1[4], bV[4];
    #pragma unroll
    for (int kb = 0; kb < 4; ++kb) {
        #pragma unroll
        for (int j = 0; j < 8; ++j) {
            const int k = kb * 32 + mq * 8 + j;
            bS0[kb][j] = f2bf(W1s[k * 32 + o]);
            bS1[kb][j] = f2bf(W1s[k * 32 + 16 + o]);
            bV [kb][j] = f2bf(W1v[k * 16 + o]);
        }
    }
    // ---- one-time: layer-2 weights (fp32, per-lane) ----
    const int e = o;
    float wcr[16];
    #pragma unroll
    for (int j = 0; j < 16; ++j)
        wcr[j] = (e < 10) ? W2s[j * 10 + e] : W2v[j];
    const float b2e = (e < 10) ? b2s[e] : 0.0f;
    const float b1a = b1s[o];
    const float b1b = b1s[16 + o];

    const int NT = N >> 4;                 // 6250 tiles
    const int wstride = gridDim.x << 2;
    const int wt0 = (blockIdx.x << 2) + wave;

    float4 LS[4][2], LV[4][6];
    if (wt0 < NT) {
        const float* xp = x + (size_t)((wt0 << 4) + o) * 512;
        #pragma unroll
        for (int kb = 0; kb < 4; ++kb) {
            LS[kb][0] = *(const float4*)(xp + kb * 32 + mq * 8);
            LS[kb][1] = *(const float4*)(xp + kb * 32 + mq * 8 + 4);
            #pragma unroll
            for (int q = 0; q < 6; ++q)
                LV[kb][q] = *(const float4*)(xp + 128 + kb * 96 + mq * 24 + q * 4);
        }
    }

    for (int wt = wt0; wt < NT; wt += wstride) {
        const int base = wt << 4;
        const int nxt  = wt + wstride;
        const int nb   = (nxt < NT) ? nxt : wt;          // clamped prefetch
        const float* xq = x + (size_t)((nb << 4) + o) * 512;

        f32x4 accS0 = {0.f,0.f,0.f,0.f}, accS1 = {0.f,0.f,0.f,0.f};
        f32x4 accV0 = {0.f,0.f,0.f,0.f}, accV1 = {0.f,0.f,0.f,0.f};
        f32x4 accV2 = {0.f,0.f,0.f,0.f};

        // ---- S phase: convert -> reissue -> MFMA, per k-block ----
        #pragma unroll
        for (int kb = 0; kb < 4; ++kb) {
            i32x4 wv;
            wv[0] = (int)cvtpk(LS[kb][0].x, LS[kb][0].y);
            wv[1] = (int)cvtpk(LS[kb][0].z, LS[kb][0].w);
            wv[2] = (int)cvtpk(LS[kb][1].x, LS[kb][1].y);
            wv[3] = (int)cvtpk(LS[kb][1].z, LS[kb][1].w);
            LS[kb][0] = *(const float4*)(xq + kb * 32 + mq * 8);      // prefetch t+1
            LS[kb][1] = *(const float4*)(xq + kb * 32 + mq * 8 + 4);
            const bf16x8 a = __builtin_bit_cast(bf16x8, wv);
            accS0 = __builtin_amdgcn_mfma_f32_16x16x32_bf16(a, bS0[kb], accS0, 0, 0, 0);
            accS1 = __builtin_amdgcn_mfma_f32_16x16x32_bf16(a, bS1[kb], accS1, 0, 0, 0);
        }

        // ---- V phase: convert + stride-3 de-interleave -> reissue -> MFMA ----
        #pragma unroll
        for (int kb = 0; kb < 4; ++kb) {
            unsigned p[12];
            #pragma unroll
            for (int q = 0; q < 6; ++q) {
                p[2*q]   = cvtpk(LV[kb][q].x, LV[kb][q].y);
                p[2*q+1] = cvtpk(LV[kb][q].z, LV[kb][q].w);
            }
            #pragma unroll
            for (int q = 0; q < 6; ++q)                               // prefetch t+1
                LV[kb][q] = *(const float4*)(xq + 128 + kb * 96 + mq * 24 + q * 4);
            i32x4 w0, w1, w2;
            #pragma unroll
            for (int w = 0; w < 4; ++w) {
                // a0[w] = (t[6w],   t[6w+3]) = (p[3w].lo,   p[3w+1].hi)
                w0[w] = (int)__builtin_amdgcn_perm(p[3*w+1], p[3*w],   0x07060100u);
                // a1[w] = (t[6w+1], t[6w+4]) = (p[3w].hi,   p[3w+2].lo)
                w1[w] = (int)__builtin_amdgcn_perm(p[3*w+2], p[3*w],   0x05040302u);
                // a2[w] = (t[6w+2], t[6w+5]) = (p[3w+1].lo, p[3w+2].hi)
                w2[w] = (int)__builtin_amdgcn_perm(p[3*w+2], p[3*w+1], 0x07060100u);
            }
            const bf16x8 a0 = __builtin_bit_cast(bf16x8, w0);
            const bf16x8 a1 = __builtin_bit_cast(bf16x8, w1);
            const bf16x8 a2 = __builtin_bit_cast(bf16x8, w2);
            accV0 = __builtin_amdgcn_mfma_f32_16x16x32_bf16(a0, bV[kb], accV0, 0, 0, 0);
            accV1 = __builtin_amdgcn_mfma_f32_16x16x32_bf16(a1, bV[kb], accV1, 0, 0, 0);
            accV2 = __builtin_amdgcn_mfma_f32_16x16x32_bf16(a2, bV[kb], accV2, 0, 0, 0);
        }

        // ---- epilogue: lane-local silu + gating -> sred ----
        #pragma unroll
        for (int v = 0; v < 4; ++v) {
            const float hs = fmaf(accS0[v], inv1, b1a);
            const float hg = fmaf(accS1[v], inv1, b1b);
            const float s  = hs / (1.f + __expf(-hs));
            const float g  = hg / (1.f + __expf(-hg));
            const float gm = g * inv1;
            const int  r   = mq * 4 + v;
            sred[wave][r][o]      = s;
            sred[wave][r][16 + o] = gm * accV0[v];
            sred[wave][r][32 + o] = gm * accV1[v];
            sred[wave][r][48 + o] = gm * accV2[v];
        }
        asm volatile("s_waitcnt lgkmcnt(0)" ::: "memory");

        // ---- layer 2: lane e<13, dot-16 for rows mq, mq+4, mq+8, mq+12 ----
        #pragma unroll
        for (int w = 0; w < 4; ++w) {
            const int r = (w << 2) + mq;
            if (e < 13) {
                const int slot = (e < 10) ? 0 : (e - 9);
                const float4* pp = (const float4*)(&sred[wave][r][slot * 16]);
                float sum = 0.f;
                #pragma unroll
                for (int q = 0; q < 4; ++q) {
                    float4 pv = pp[q];
                    sum = fmaf(pv.x, wcr[q * 4 + 0], sum);
                    sum = fmaf(pv.y, wcr[q * 4 + 1], sum);
                    sum = fmaf(pv.z, wcr[q * 4 + 2], sum);
                    sum = fmaf(pv.w, wcr[q * 4 + 3], sum);
                }
                out[(size_t)(base + r) * 13 + e] = fmaf(sum, 0.25f, b2e);
            }
        }
        asm volatile("s_waitcnt lgkmcnt(0)" ::: "memory");  // sred reads done
    }
}

extern "C" void kernel_launch(void* const* d_in, const int* in_sizes, int n_in,
                              void* d_out, int out_size, void* d_ws, size_t ws_size,
                              hipStream_t stream) {
    const float* x   = (const float*)d_in[0];
    const float* W1s = (const float*)d_in[1];
    const float* W1v = (const float*)d_in[2];
    const float* b1s = (const float*)d_in[3];
    const float* W2s = (const float*)d_in[4];
    const float* W2v = (const float*)d_in[5];
    const float* b2s = (const float*)d_in[6];
    float* outp = (float*)d_out;
    const int N = in_sizes[0] / 512;   // 100000
    nlrb_kernel<<<dim3(512), dim3(BLOCK), 0, stream>>>(
        x, W1s, W1v, b1s, W2s, W2v, b2s, outp, N);
}